// Round 1
// baseline (313.581 us; speedup 1.0000x reference)
//
#include <hip/hip_runtime.h>

#define B_ 4
#define C_ 32
#define N_ 8192
#define S_ 8
#define P_ 1024

#define PI_F 3.14159265358979f
#define TWOPI_F 6.28318530717959f

// block-wide reduce (all threads must call); returns reduced value to all threads
__device__ __forceinline__ float blk_red(float v, float* red, bool is_min){
  int tid = threadIdx.x;
  red[tid] = v; __syncthreads();
  for (int off = blockDim.x >> 1; off > 0; off >>= 1){
    if (tid < off) red[tid] = is_min ? fminf(red[tid], red[tid+off]) : fmaxf(red[tid], red[tid+off]);
    __syncthreads();
  }
  float r = red[0]; __syncthreads();
  return r;
}

// ---------------- K1: gather loc, normalize omega per (b,s,dim) ----------------
__global__ __launch_bounds__(256) void k_om(const float* __restrict__ loc,
                                            const int* __restrict__ ind,
                                            float* __restrict__ om){
  int b = blockIdx.x >> 3, s = blockIdx.x & 7;
  int tid = threadIdx.x;
  __shared__ float l0[P_], l1[P_];
  __shared__ float red[256];
  const int* indb = ind + b*N_ + s*P_;
  float mn0=1e30f, mx0=-1e30f, mn1=1e30f, mx1=-1e30f;
  for (int p = tid; p < P_; p += 256){
    int n = indb[p];
    float a = loc[(b*N_ + n)*2];
    float c = loc[(b*N_ + n)*2 + 1];
    l0[p] = a; l1[p] = c;
    mn0 = fminf(mn0, a); mx0 = fmaxf(mx0, a);
    mn1 = fminf(mn1, c); mx1 = fmaxf(mx1, c);
  }
  mn0 = blk_red(mn0, red, true);  mx0 = blk_red(mx0, red, false);
  mn1 = blk_red(mn1, red, true);  mx1 = blk_red(mx1, red, false);
  float i0 = TWOPI_F / (mx0 - mn0 + 1e-6f);
  float i1 = TWOPI_F / (mx1 - mn1 + 1e-6f);
  float* om0 = om + ((b*S_ + s)*2)*P_;
  float* om1 = om0 + P_;
  for (int p = tid; p < P_; p += 256){
    om0[p] = (l0[p] - mn0)*i0 - PI_F;
    om1[p] = (l1[p] - mn1)*i1 - PI_F;
  }
}

// ---------------- K2: gather xg per (b,s,c), min/max over p ----------------
__global__ __launch_bounds__(256) void k_xg(const float* __restrict__ x,
                                            const int* __restrict__ ind,
                                            float* __restrict__ xg,
                                            float* __restrict__ xmn,
                                            float* __restrict__ xmx){
  int blk = blockIdx.x;
  int c = blk & 31, s = (blk >> 5) & 7, b = blk >> 8;
  int tid = threadIdx.x;
  const int* indb = ind + b*N_ + s*P_;
  const float* xr = x + (b*C_ + c)*N_;
  float* xgr = xg + ((b*S_ + s)*C_ + c)*P_;
  __shared__ float red[256];
  float mn = 1e30f, mx = -1e30f;
  for (int p = tid; p < P_; p += 256){
    float v = xr[indb[p]];
    xgr[p] = v;
    mn = fminf(mn, v); mx = fmaxf(mx, v);
  }
  mn = blk_red(mn, red, true); mx = blk_red(mx, red, false);
  if (tid == 0){ xmn[(b*C_ + c)*S_ + s] = mn; xmx[(b*C_ + c)*S_ + s] = mx; }
}

// ---------------- K3: forward NUDFT: coef[b,s,x,y,c] (y=0..12) ----------------
// grid = (b,s,x) = 800 blocks, 448 threads; thread t<416 -> (c=t/13, y=t%13)
__global__ __launch_bounds__(448) void k_fwd(const float* __restrict__ om,
                                             const float* __restrict__ xg,
                                             float* __restrict__ coef){
  int blk = blockIdx.x;
  int xo = blk % 25;
  int s  = (blk / 25) & 7;
  int b  = blk / 200;
  int t = threadIdx.x;
  __shared__ float xgs[32*132];       // padded stride 132: conflict-free c-strided reads
  __shared__ float Ws[128*13*2];      // W[p][y] complex = e1(x)*e2(y) for this block's x
  const float kxv = (float)(xo - 12);
  const float* om0 = om + ((b*S_ + s)*2)*P_;
  const float* om1 = om0 + P_;
  const float* xgb = xg + ((b*S_ + s)*C_)*P_;
  int c = t / 13, y = t - c*13;       // valid for t<416
  float accre = 0.f, accim = 0.f;
  for (int pc = 0; pc < P_; pc += 128){
    // stage xg chunk [32][128]
    for (int i = t; i < 32*128; i += 448){
      int cc = i >> 7, pp = i & 127;
      xgs[cc*132 + pp] = xgb[cc*P_ + pc + pp];
    }
    // build W chunk (lanes 0..127, one p each)
    if (t < 128){
      float o0 = om0[pc + t], o1 = om1[pc + t];
      float sa, ca; __sincosf(o0*kxv, &sa, &ca);
      float e1re = ca, e1im = -sa;                 // exp(-i*om0*kx)
      float s12, c12; __sincosf(12.f*o1, &s12, &c12);
      float e2re = c12, e2im = s12;                // exp(+12i*om1) = e2 at y=0
      float sd, cd; __sincosf(o1, &sd, &cd);
      float dre = cd, dim = -sd;                   // exp(-i*om1)
      float* wp = Ws + t*26;
      #pragma unroll
      for (int yy = 0; yy < 13; ++yy){
        wp[yy*2]   = e1re*e2re - e1im*e2im;
        wp[yy*2+1] = e1re*e2im + e1im*e2re;
        float nre = e2re*dre - e2im*dim;
        float nim = e2re*dim + e2im*dre;
        e2re = nre; e2im = nim;
      }
    }
    __syncthreads();
    if (t < 416){
      const float* xc = xgs + c*132;
      #pragma unroll 4
      for (int p = 0; p < 128; ++p){
        float g = xc[p];
        float wre = Ws[(p*13 + y)*2], wim = Ws[(p*13 + y)*2 + 1];
        accre += g*wre;
        accim += g*wim;
      }
    }
    __syncthreads();
  }
  if (t < 416){
    int oidx = ((((b*S_ + s)*25 + xo)*13 + y)*C_ + c)*2;
    coef[oidx]   = accre * 0.04f;   // * norm = 1/25
    coef[oidx+1] = accim * 0.04f;
  }
}

// ---------------- K4: spectral sandwich: s-contract, channel-mix, s-broadcast ----
// grid = b*313; q<300 -> i1 path (x=q/12,y=q%12); q>=300 -> i2 path (x=q-300, y=12)
__global__ __launch_bounds__(64) void k_mid(const float* __restrict__ coef,
    const float* __restrict__ w1s_re, const float* __restrict__ w1s_im,
    const float* __restrict__ w2s_re, const float* __restrict__ w2s_im,
    const float* __restrict__ w1_re,  const float* __restrict__ w1_im,
    const float* __restrict__ w2_re,  const float* __restrict__ w2_im,
    const float* __restrict__ w1sb_re,const float* __restrict__ w1sb_im,
    const float* __restrict__ w2sb_re,const float* __restrict__ w2sb_im,
    float* __restrict__ i1sb, float* __restrict__ i2sb){
  int blk = blockIdx.x;
  int b = blk / 313, q = blk - b*313;
  int lane = threadIdx.x;
  __shared__ float iv[32*2];
  bool p1 = (q < 300);
  int x = p1 ? q/12 : q - 300;
  int y = p1 ? q%12 : 12;
  if (lane < 32){
    float are = 0.f, aim = 0.f;
    for (int s = 0; s < 8; ++s){
      int ci = ((((b*S_ + s)*25 + x)*13 + y)*C_ + lane)*2;
      float zre = coef[ci], zim = coef[ci+1];
      float wre, wim;
      if (p1){ wre = w1s_re[(s*25+x)*12+y]; wim = w1s_im[(s*25+x)*12+y]; }
      else   { wre = w2s_re[s*13+x];        wim = w2s_im[s*13+x]; }
      are += zre*wre - zim*wim;
      aim += zre*wim + zim*wre;
    }
    iv[lane*2] = are; iv[lane*2+1] = aim;
  }
  __syncthreads();
  if (lane < 32){
    float ore = 0.f, oim = 0.f;
    for (int i = 0; i < 32; ++i){
      float zre = iv[i*2], zim = iv[i*2+1];
      float wre, wim;
      if (p1){ int wi = ((i*C_ + lane)*25 + x)*12 + y; wre = w1_re[wi]; wim = w1_im[wi]; }
      else   { int wi = (i*C_ + lane)*13 + x;          wre = w2_re[wi]; wim = w2_im[wi]; }
      ore += zre*wre - zim*wim;
      oim += zre*wim + zim*wre;
    }
    for (int s = 0; s < 8; ++s){
      float wre, wim, scale;
      if (p1){ wre = w1sb_re[(s*25+x)*12+y]; wim = w1sb_im[(s*25+x)*12+y]; scale = 0.08f; }           // 2/25
      else   { wre = w2sb_re[s*13+x];        wim = w2sb_im[s*13+x];        scale = (x==12)?0.04f:0.08f; } // center mode: 1/25
      float zre = (ore*wre - oim*wim)*scale;
      float zim = (ore*wim + oim*wre)*scale;
      if (p1){ int oi = (((b*C_ + lane)*S_ + s)*300 + x*12 + y)*2; i1sb[oi] = zre; i1sb[oi+1] = zim; }
      else   { int oi = (((b*C_ + lane)*S_ + s)*13  + x)*2;        i2sb[oi] = zre; i2sb[oi+1] = zim; }
    }
  }
}

// ---------------- K5: inverse NUDFT (Hermitian-folded, real), renorm, scatter ----
// grid = (b,s,o) = 1024 blocks, 256 threads, 4 points each
__global__ __launch_bounds__(256) void k_inv(const float* __restrict__ om,
    const float* __restrict__ i1sb, const float* __restrict__ i2sb,
    const float* __restrict__ xmn, const float* __restrict__ xmx,
    const int* __restrict__ ind, float* __restrict__ out){
  int blk = blockIdx.x;
  int o = blk & 31, s = (blk >> 5) & 7, b = blk >> 8;
  int tid = threadIdx.x;
  const float* om0 = om + ((b*S_ + s)*2)*P_;
  const float* om1 = om0 + P_;
  const float* z1 = i1sb + (((b*C_ + o)*S_ + s)*300)*2;   // block-uniform -> scalarized loads
  const float* z2 = i2sb + (((b*C_ + o)*S_ + s)*13)*2;
  __shared__ float red[256];
  float rloc[4];
  float mn = 1e30f, mx = -1e30f;
  for (int pi = 0; pi < 4; ++pi){
    int p = tid + pi*256;
    float o0 = om0[p], o1 = om1[p];
    // c1[x] = conj(E1) = exp(+i*om0*(x-12)), built by recurrence
    float c1re[25], c1im[25];
    float sa, ca; __sincosf(12.f*o0, &sa, &ca);
    c1re[0] = ca; c1im[0] = -sa;                  // exp(-12i*om0)
    float sd, cd; __sincosf(o0, &sd, &cd);        // d1 = exp(+i*om0)
    #pragma unroll
    for (int xx = 1; xx < 25; ++xx){
      float pre = c1re[xx-1], pim = c1im[xx-1];
      c1re[xx] = pre*cd - pim*sd;
      c1im[xx] = pre*sd + pim*cd;
    }
    // y=12 column (e2 term = 1): r += Re(z2[x]*c1[x]), x=0..12
    float r = 0.f;
    #pragma unroll
    for (int xx = 0; xx < 13; ++xx)
      r += z2[xx*2]*c1re[xx] - z2[xx*2+1]*c1im[xx];
    // y=0..11: A_y = sum_x z1[x,y]*c1[x];  r += Re(A_y * c2[y])
    float sb, cb; __sincosf(12.f*o1, &sb, &cb);
    float c2re = cb, c2im = -sb;                  // exp(-12i*om1)
    float sd2, cd2; __sincosf(o1, &sd2, &cd2);    // d2 = exp(+i*om1)
    for (int yy = 0; yy < 12; ++yy){
      float Are = 0.f, Aim = 0.f;
      #pragma unroll
      for (int xx = 0; xx < 25; ++xx){
        float zre = z1[(xx*12 + yy)*2], zim = z1[(xx*12 + yy)*2 + 1];
        Are += zre*c1re[xx] - zim*c1im[xx];
        Aim += zre*c1im[xx] + zim*c1re[xx];
      }
      r += Are*c2re - Aim*c2im;
      float nre = c2re*cd2 - c2im*sd2;
      float nim = c2re*sd2 + c2im*cd2;
      c2re = nre; c2im = nim;
    }
    rloc[pi] = r;
    mn = fminf(mn, r); mx = fmaxf(mx, r);
  }
  mn = blk_red(mn, red, true);
  mx = blk_red(mx, red, false);
  float xmnv = xmn[(b*C_ + o)*S_ + s];
  float xmxv = xmx[(b*C_ + o)*S_ + s];
  float scale = (xmxv - xmnv) / (mx - mn + 1e-6f);
  const int* indb = ind + b*N_ + s*P_;
  float* outb = out + (b*C_ + o)*N_;
  for (int pi = 0; pi < 4; ++pi){
    int p = tid + pi*256;
    outb[indb[p]] = (rloc[pi] - mn)*scale + xmnv;
  }
}

extern "C" void kernel_launch(void* const* d_in, const int* in_sizes, int n_in,
                              void* d_out, int out_size, void* d_ws, size_t ws_size,
                              hipStream_t stream){
  const float* x      = (const float*)d_in[0];
  const float* loc    = (const float*)d_in[1];
  const int*   ind    = (const int*)  d_in[2];
  const float* w1s_re = (const float*)d_in[3];
  const float* w1s_im = (const float*)d_in[4];
  const float* w2s_re = (const float*)d_in[5];
  const float* w2s_im = (const float*)d_in[6];
  const float* w1_re  = (const float*)d_in[7];
  const float* w1_im  = (const float*)d_in[8];
  const float* w2_re  = (const float*)d_in[9];
  const float* w2_im  = (const float*)d_in[10];
  const float* w1sb_re= (const float*)d_in[11];
  const float* w1sb_im= (const float*)d_in[12];
  const float* w2sb_re= (const float*)d_in[13];
  const float* w2sb_im= (const float*)d_in[14];
  float* out = (float*)d_out;

  float* ws   = (float*)d_ws;
  float* om   = ws;                  // (B,S,2,P)       = 65536
  float* xg   = om   + 65536;        // (B,S,C,P)       = 1048576
  float* xmn  = xg   + 1048576;      // (B,C,S)         = 1024
  float* xmx  = xmn  + 1024;         // (B,C,S)         = 1024
  float* coef = xmx  + 1024;         // (B,S,25,13,C,2) = 665600
  float* i1sb = coef + 665600;       // (B,C,S,25,12,2) = 614400
  float* i2sb = i1sb + 614400;       // (B,C,S,13,2)    = 26624

  k_om <<<32,   256, 0, stream>>>(loc, ind, om);
  k_xg <<<1024, 256, 0, stream>>>(x, ind, xg, xmn, xmx);
  k_fwd<<<800,  448, 0, stream>>>(om, xg, coef);
  k_mid<<<1252, 64,  0, stream>>>(coef, w1s_re, w1s_im, w2s_re, w2s_im,
                                  w1_re, w1_im, w2_re, w2_im,
                                  w1sb_re, w1sb_im, w2sb_re, w2sb_im,
                                  i1sb, i2sb);
  k_inv<<<1024, 256, 0, stream>>>(om, i1sb, i2sb, xmn, xmx, ind, out);
}

// Round 3
// 210.687 us; speedup vs baseline: 1.4884x; 1.4884x over previous
//
#include <hip/hip_runtime.h>

#define B_ 4
#define C_ 32
#define N_ 8192
#define S_ 8
#define P_ 1024
#define NM_FWD 325   // 25*13 forward modes
#define NM_INV 313   // 25*12 + 13 folded inverse modes
#define NORM_F 0.04f // 1/25

#define PI_F 3.14159265358979f
#define TWOPI_F 6.28318530717959f

// block-wide reduce (all threads must call); returns reduced value to all threads
__device__ __forceinline__ float blk_red(float v, float* red, bool is_min){
  int tid = threadIdx.x;
  red[tid] = v; __syncthreads();
  for (int off = blockDim.x >> 1; off > 0; off >>= 1){
    if (tid < off) red[tid] = is_min ? fminf(red[tid], red[tid+off]) : fmaxf(red[tid], red[tid+off]);
    __syncthreads();
  }
  float r = red[0]; __syncthreads();
  return r;
}

// ---------------- K1: gather loc, normalize omega per (b,s,dim) ----------------
__global__ __launch_bounds__(256) void k_om(const float* __restrict__ loc,
                                            const int* __restrict__ ind,
                                            float* __restrict__ om){
  int b = blockIdx.x >> 3, s = blockIdx.x & 7;
  int tid = threadIdx.x;
  __shared__ float l0[P_], l1[P_];
  __shared__ float red[256];
  const int* indb = ind + b*N_ + s*P_;
  float mn0=1e30f, mx0=-1e30f, mn1=1e30f, mx1=-1e30f;
  for (int p = tid; p < P_; p += 256){
    int n = indb[p];
    float a = loc[(b*N_ + n)*2];
    float c = loc[(b*N_ + n)*2 + 1];
    l0[p] = a; l1[p] = c;
    mn0 = fminf(mn0, a); mx0 = fmaxf(mx0, a);
    mn1 = fminf(mn1, c); mx1 = fmaxf(mx1, c);
  }
  mn0 = blk_red(mn0, red, true);  mx0 = blk_red(mx0, red, false);
  mn1 = blk_red(mn1, red, true);  mx1 = blk_red(mx1, red, false);
  float i0 = TWOPI_F / (mx0 - mn0 + 1e-6f);
  float i1 = TWOPI_F / (mx1 - mn1 + 1e-6f);
  float* om0 = om + ((b*S_ + s)*2)*P_;
  float* om1 = om0 + P_;
  for (int p = tid; p < P_; p += 256){
    om0[p] = (l0[p] - mn0)*i0 - PI_F;
    om1[p] = (l1[p] - mn1)*i1 - PI_F;
  }
}

// ---------------- K2: gather x -> transposed xg_t[bs][p][c], partial min/max ----
// grid = (bs,part) = 128 blocks, 512 threads = 16 p x 32 c
__global__ __launch_bounds__(512) void k_xg(const float* __restrict__ x,
                                            const int* __restrict__ ind,
                                            float* __restrict__ xg_t,
                                            float* __restrict__ pmm){
  int blk = blockIdx.x;
  int part = blk & 3, bs = blk >> 2;
  int b = bs >> 3, s = bs & 7;
  int t = threadIdx.x;
  int c = t & 31, pl = t >> 5;
  __shared__ int inds[256];
  __shared__ float rmn[8*32], rmx[8*32];
  if (t < 256) inds[t] = ind[b*N_ + s*P_ + part*256 + t];
  __syncthreads();
  const float* xr = x + (b*C_ + c)*N_;
  float mn = 1e30f, mx = -1e30f;
  int pbase = part*256;
  for (int k = 0; k < 16; ++k){
    int pp = pl + k*16;
    float v = xr[inds[pp]];
    xg_t[(bs*P_ + pbase + pp)*C_ + c] = v;
    mn = fminf(mn, v); mx = fmaxf(mx, v);
  }
  mn = fminf(mn, __shfl_xor(mn, 32));
  mx = fmaxf(mx, __shfl_xor(mx, 32));
  int wid = t >> 6;
  if ((t & 63) < 32){ rmn[wid*32 + c] = mn; rmx[wid*32 + c] = mx; }
  __syncthreads();
  if (t < 32){
    float m0 = rmn[t], M0 = rmx[t];
    #pragma unroll
    for (int w = 1; w < 8; ++w){ m0 = fminf(m0, rmn[w*32+t]); M0 = fmaxf(M0, rmx[w*32+t]); }
    pmm[((bs*4 + part)*32 + t)*2]     = m0;
    pmm[((bs*4 + part)*32 + t)*2 + 1] = M0;
  }
}

// ---------------- K3: forward NUDFT as tiled dense MAC ----------------
// grid = (bs 32) x (mode-tile 6) x (p-part 2) = 384 blocks, 448 threads = 56 m x 8 cq
__global__ __launch_bounds__(448) void k_fwd(const float* __restrict__ om,
                                             const float* __restrict__ xg_t,
                                             float* __restrict__ coef_part){
  int blk = blockIdx.x;
  int part = blk & 1;
  int tile = (blk >> 1) % 6;
  int bs   = blk / 12;
  int t = threadIdx.x;
  int ml = t >> 3;          // 0..55
  int q  = t & 7;           // c-quad
  int mf = tile*56 + ml;
  int mfc = min(mf, NM_FWD-1);
  int xo = mfc / 13, yo = mfc - xo*13;
  float kx = (float)(xo - 12), ky = (float)(yo - 12);
  __shared__ float o0s[512], o1s[512];
  __shared__ __align__(16) float xgs[64*32];
  __shared__ float Wre[56*68], Wim[56*68];
  const float* om0 = om + bs*2*P_;
  const float* om1 = om0 + P_;
  // stage omega for this block's p-range once
  for (int i = t; i < 512; i += 448){
    o0s[i] = om0[part*512 + i];
    o1s[i] = om1[part*512 + i];
  }
  float ar[4] = {0,0,0,0}, ai[4] = {0,0,0,0};
  for (int ch = 0; ch < 8; ++ch){
    int pbase = part*512 + ch*64;
    __syncthreads();
    // stage xg chunk [64 p][32 c] via float4
    for (int i = t; i < 512; i += 448){
      ((float4*)xgs)[i] = ((const float4*)xg_t)[(bs*P_ + pbase + (i>>3))*8 + (i&7)];
    }
    // build W for this thread's mode (8 p's)
    {
      int ps = t & 7;
      #pragma unroll
      for (int k = 0; k < 8; ++k){
        int p = ps + k*8;
        float th = o0s[ch*64 + p]*kx + o1s[ch*64 + p]*ky;
        float sn, cs; __sincosf(th, &sn, &cs);
        Wre[ml*68 + p] = cs;
        Wim[ml*68 + p] = sn;
      }
    }
    __syncthreads();
    #pragma unroll 8
    for (int p = 0; p < 64; ++p){
      float4 g4 = *(const float4*)&xgs[p*32 + q*4];
      float wre = Wre[ml*68 + p], wim = Wim[ml*68 + p];
      ar[0] += g4.x*wre; ai[0] += g4.x*wim;
      ar[1] += g4.y*wre; ai[1] += g4.y*wim;
      ar[2] += g4.z*wre; ai[2] += g4.z*wim;
      ar[3] += g4.w*wre; ai[3] += g4.w*wim;
    }
  }
  if (mf < NM_FWD){
    float* dst = coef_part + (size_t)((part*32 + bs)*NM_FWD + mf)*64 + q*8;
    #pragma unroll
    for (int j = 0; j < 4; ++j){
      dst[j*2]     = ar[j]*NORM_F;     // Re: sum g*cos
      dst[j*2 + 1] = -ai[j]*NORM_F;    // Im of e^{-i phi}: -sum g*sin
    }
  }
}

// ---------------- K4: spectral sandwich (full-wave, part-sum fused) ----------------
// grid = b*313 blocks, 64 threads; lanes 0-31 / 32-63 split the serial loops
__global__ __launch_bounds__(64) void k_mid(const float* __restrict__ coef_part,
    const float* __restrict__ w1s_re, const float* __restrict__ w1s_im,
    const float* __restrict__ w2s_re, const float* __restrict__ w2s_im,
    const float* __restrict__ w1_re,  const float* __restrict__ w1_im,
    const float* __restrict__ w2_re,  const float* __restrict__ w2_im,
    const float* __restrict__ w1sb_re,const float* __restrict__ w1sb_im,
    const float* __restrict__ w2sb_re,const float* __restrict__ w2sb_im,
    float* __restrict__ zbuf){
  int blk = blockIdx.x;
  int b = blk / NM_INV, q = blk - b*NM_INV;
  int lane = threadIdx.x;
  int o = lane & 31;
  int hi = lane >> 5;
  bool p1 = (q < 300);
  int x = p1 ? q/12 : q - 300;
  int y = p1 ? q - (q/12)*12 : 12;
  int mf = x*13 + y;
  __shared__ float iv[64];
  // phase 1: s-contract; lower lanes take part 0, upper part 1
  float are = 0.f, aim = 0.f;
  for (int s = 0; s < 8; ++s){
    const float* cp = coef_part + (size_t)((hi*32 + b*8 + s)*NM_FWD + mf)*64 + o*2;
    float cre = cp[0], cim = cp[1];
    float wre, wim;
    if (p1){ int wi = (s*25+x)*12+y; wre = w1s_re[wi]; wim = w1s_im[wi]; }
    else   { int wi = s*13+x;        wre = w2s_re[wi]; wim = w2s_im[wi]; }
    are += cre*wre - cim*wim;
    aim += cre*wim + cim*wre;
  }
  are += __shfl_xor(are, 32);
  aim += __shfl_xor(aim, 32);
  if (hi == 0){ iv[o*2] = are; iv[o*2+1] = aim; }
  __syncthreads();
  // phase 2: 32x32 channel mix; halves split the i-loop
  float ore = 0.f, oim = 0.f;
  for (int ii = 0; ii < 16; ++ii){
    int i = hi*16 + ii;
    float zre = iv[i*2], zim = iv[i*2+1];
    float wre, wim;
    if (p1){ int wi = ((i*32 + o)*25 + x)*12 + y; wre = w1_re[wi]; wim = w1_im[wi]; }
    else   { int wi = (i*32 + o)*13 + x;          wre = w2_re[wi]; wim = w2_im[wi]; }
    ore += zre*wre - zim*wim;
    oim += zre*wim + zim*wre;
  }
  ore += __shfl_xor(ore, 32);
  oim += __shfl_xor(oim, 32);
  // phase 3: s-broadcast; halves split the s-loop
  for (int si = 0; si < 4; ++si){
    int s = hi*4 + si;
    float wre, wim, scale;
    if (p1){ int wi = (s*25+x)*12+y; wre = w1sb_re[wi]; wim = w1sb_im[wi]; scale = 0.08f; }
    else   { int wi = s*13+x;        wre = w2sb_re[wi]; wim = w2sb_im[wi]; scale = (x==12)?0.04f:0.08f; }
    float zre = (ore*wre - oim*wim)*scale;
    float zim = (ore*wim + oim*wre)*scale;
    size_t oi = (size_t)((b*8 + s)*NM_INV + q)*64 + o*2;
    zbuf[oi] = zre; zbuf[oi+1] = zim;
  }
}

// ---------------- K5: inverse NUDFT as real dot over 313 folded modes ----------------
// grid = (bs 32) x (p-tile 16) = 512 blocks, 512 threads = 8 oq x 64 p
__global__ __launch_bounds__(512) void k_inv(const float* __restrict__ om,
                                             const float* __restrict__ zbuf,
                                             float* __restrict__ routc){
  int blk = blockIdx.x;
  int pt = blk & 15, bs = blk >> 4;
  int p0 = pt*64;
  int t = threadIdx.x;
  int oq = t >> 6, pl = t & 63;
  __shared__ float o0s[64], o1s[64];
  __shared__ float F1[64*66], F2[64*66];
  __shared__ __align__(16) float Zs[64*64];
  const float* om0 = om + bs*2*P_;
  if (t < 64) o0s[t] = om0[p0 + t];
  else if (t < 128) o1s[t-64] = om0[P_ + p0 + t - 64];
  float acc[4] = {0,0,0,0};
  for (int chv = 0; chv < 5; ++chv){
    int m0 = chv*64;
    __syncthreads();
    // stage Z chunk [64 m][32 o][2] (zero-pad past 313)
    for (int i = t; i < 4096; i += 512){
      int m = i >> 6, rest = i & 63;
      Zs[i] = (m0 + m < NM_INV) ? zbuf[(size_t)(bs*NM_INV + m0 + m)*64 + rest] : 0.f;
    }
    // build F chunk: F1=cos(theta), F2=sin(theta), theta = om0*kx + om1*ky
    {
      int ml = t >> 3, ps = t & 7;
      int mg = min(m0 + ml, NM_INV-1);
      float kx, ky;
      if (mg < 300){ int xx = mg/12; kx = (float)(xx - 12); ky = (float)(mg - xx*12 - 12); }
      else { kx = (float)(mg - 312); ky = 0.f; }
      #pragma unroll
      for (int k = 0; k < 8; ++k){
        int p = ps + k*8;
        float th = o0s[p]*kx + o1s[p]*ky;
        float sn, cs; __sincosf(th, &sn, &cs);
        F1[ml*66 + p] = cs;
        F2[ml*66 + p] = sn;
      }
    }
    __syncthreads();
    #pragma unroll 4
    for (int m = 0; m < 64; ++m){
      float f1 = F1[m*66 + pl], f2 = F2[m*66 + pl];
      float4 za = *(const float4*)&Zs[m*64 + oq*8];
      float4 zb = *(const float4*)&Zs[m*64 + oq*8 + 4];
      acc[0] += za.x*f1 - za.y*f2;
      acc[1] += za.z*f1 - za.w*f2;
      acc[2] += zb.x*f1 - zb.y*f2;
      acc[3] += zb.z*f1 - zb.w*f2;
    }
  }
  #pragma unroll
  for (int j = 0; j < 4; ++j){
    routc[(size_t)(bs*C_ + oq*4 + j)*P_ + p0 + pl] = acc[j];
  }
}

// ---------------- K6: renorm + inverse-permutation scatter ----------------
// grid = (b,s,o) = 1024 blocks, 256 threads x 4 points
__global__ __launch_bounds__(256) void k_fin(const float* __restrict__ routc,
                                             const float* __restrict__ pmm,
                                             const int* __restrict__ ind,
                                             float* __restrict__ out){
  int blk = blockIdx.x;
  int o = blk & 31, s = (blk >> 5) & 7, b = blk >> 8;
  int bs = b*8 + s;
  int t = threadIdx.x;
  __shared__ float red[256];
  const float* rr = routc + (size_t)(bs*C_ + o)*P_;
  float v[4]; float mn = 1e30f, mx = -1e30f;
  #pragma unroll
  for (int k = 0; k < 4; ++k){
    v[k] = rr[t + k*256];
    mn = fminf(mn, v[k]); mx = fmaxf(mx, v[k]);
  }
  mn = blk_red(mn, red, true);
  mx = blk_red(mx, red, false);
  float xmn = 1e30f, xmx = -1e30f;
  #pragma unroll
  for (int part = 0; part < 4; ++part){
    xmn = fminf(xmn, pmm[((bs*4+part)*32 + o)*2]);
    xmx = fmaxf(xmx, pmm[((bs*4+part)*32 + o)*2 + 1]);
  }
  float scale = (xmx - xmn) / (mx - mn + 1e-6f);
  const int* indb = ind + b*N_ + s*P_;
  float* outb = out + (size_t)(b*C_ + o)*N_;
  #pragma unroll
  for (int k = 0; k < 4; ++k){
    int p = t + k*256;
    outb[indb[p]] = (v[k] - mn)*scale + xmn;
  }
}

extern "C" void kernel_launch(void* const* d_in, const int* in_sizes, int n_in,
                              void* d_out, int out_size, void* d_ws, size_t ws_size,
                              hipStream_t stream){
  const float* x      = (const float*)d_in[0];
  const float* loc    = (const float*)d_in[1];
  const int*   ind    = (const int*)  d_in[2];
  const float* w1s_re = (const float*)d_in[3];
  const float* w1s_im = (const float*)d_in[4];
  const float* w2s_re = (const float*)d_in[5];
  const float* w2s_im = (const float*)d_in[6];
  const float* w1_re  = (const float*)d_in[7];
  const float* w1_im  = (const float*)d_in[8];
  const float* w2_re  = (const float*)d_in[9];
  const float* w2_im  = (const float*)d_in[10];
  const float* w1sb_re= (const float*)d_in[11];
  const float* w1sb_im= (const float*)d_in[12];
  const float* w2sb_re= (const float*)d_in[13];
  const float* w2sb_im= (const float*)d_in[14];
  float* out = (float*)d_out;

  float* ws = (float*)d_ws;
  float* om        = ws;                    // (B,S,2,P)              =    65,536
  float* xg_t      = om + 65536;            // (B,S,P,C)              = 1,048,576  (aliased by routc)
  float* pmm       = xg_t + 1048576;        // (B,S,4part,C,2)        =     8,192
  float* coef_part = pmm + 8192;            // (2,B,S,325,C,2)        = 1,331,200
  float* zbuf      = coef_part + 1331200;   // (B,S,313,C,2)          =   641,024
  float* routc     = xg_t;                  // (B,S,C,P) alias: xg_t dead after k_fwd

  k_om <<<32,   256, 0, stream>>>(loc, ind, om);
  k_xg <<<128,  512, 0, stream>>>(x, ind, xg_t, pmm);
  k_fwd<<<384,  448, 0, stream>>>(om, xg_t, coef_part);
  k_mid<<<4*NM_INV, 64, 0, stream>>>(coef_part, w1s_re, w1s_im, w2s_re, w2s_im,
                                     w1_re, w1_im, w2_re, w2_im,
                                     w1sb_re, w1sb_im, w2sb_re, w2sb_im, zbuf);
  k_inv<<<512,  512, 0, stream>>>(om, zbuf, routc);
  k_fin<<<1024, 256, 0, stream>>>(routc, pmm, ind, out);
}

// Round 6
// 209.614 us; speedup vs baseline: 1.4960x; 1.0051x over previous
//
#include <hip/hip_runtime.h>

#define B_ 4
#define C_ 32
#define N_ 8192
#define S_ 8
#define P_ 1024
#define NM_FWD 325   // 25*13 forward modes
#define NM_INV 313   // 25*12 + 13 folded inverse modes (y-major order: q = y*25+x, tail y=12)
#define NORM_F 0.04f // 1/25

#define PI_F 3.14159265358979f
#define TWOPI_F 6.28318530717959f

// block-wide reduce (all threads must call); returns reduced value to all threads
__device__ __forceinline__ float blk_red(float v, float* red, bool is_min){
  int tid = threadIdx.x;
  red[tid] = v; __syncthreads();
  for (int off = blockDim.x >> 1; off > 0; off >>= 1){
    if (tid < off) red[tid] = is_min ? fminf(red[tid], red[tid+off]) : fmaxf(red[tid], red[tid+off]);
    __syncthreads();
  }
  float r = red[0]; __syncthreads();
  return r;
}

// ---------------- K1: gather loc, normalize omega per (b,s,dim) ----------------
__global__ __launch_bounds__(256) void k_om(const float* __restrict__ loc,
                                            const int* __restrict__ ind,
                                            float* __restrict__ om){
  int b = blockIdx.x >> 3, s = blockIdx.x & 7;
  int tid = threadIdx.x;
  __shared__ float l0[P_], l1[P_];
  __shared__ float red[256];
  const int* indb = ind + b*N_ + s*P_;
  float mn0=1e30f, mx0=-1e30f, mn1=1e30f, mx1=-1e30f;
  for (int p = tid; p < P_; p += 256){
    int n = indb[p];
    float a = loc[(b*N_ + n)*2];
    float c = loc[(b*N_ + n)*2 + 1];
    l0[p] = a; l1[p] = c;
    mn0 = fminf(mn0, a); mx0 = fmaxf(mx0, a);
    mn1 = fminf(mn1, c); mx1 = fmaxf(mx1, c);
  }
  mn0 = blk_red(mn0, red, true);  mx0 = blk_red(mx0, red, false);
  mn1 = blk_red(mn1, red, true);  mx1 = blk_red(mx1, red, false);
  float i0 = TWOPI_F / (mx0 - mn0 + 1e-6f);
  float i1 = TWOPI_F / (mx1 - mn1 + 1e-6f);
  float* om0 = om + ((b*S_ + s)*2)*P_;
  float* om1 = om0 + P_;
  for (int p = tid; p < P_; p += 256){
    om0[p] = (l0[p] - mn0)*i0 - PI_F;
    om1[p] = (l1[p] - mn1)*i1 - PI_F;
  }
}

// ---------------- K2: gather x -> transposed xg_t[bs][p][c], partial min/max ----
// grid = (bs,part) = 128 blocks, 512 threads = 16 p x 32 c
__global__ __launch_bounds__(512) void k_xg(const float* __restrict__ x,
                                            const int* __restrict__ ind,
                                            float* __restrict__ xg_t,
                                            float* __restrict__ pmm){
  int blk = blockIdx.x;
  int part = blk & 3, bs = blk >> 2;
  int b = bs >> 3, s = bs & 7;
  int t = threadIdx.x;
  int c = t & 31, pl = t >> 5;
  __shared__ int inds[256];
  __shared__ float rmn[8*32], rmx[8*32];
  if (t < 256) inds[t] = ind[b*N_ + s*P_ + part*256 + t];
  __syncthreads();
  const float* xr = x + (b*C_ + c)*N_;
  float mn = 1e30f, mx = -1e30f;
  int pbase = part*256;
  #pragma unroll 4
  for (int k = 0; k < 16; ++k){
    int pp = pl + k*16;
    float v = xr[inds[pp]];
    xg_t[(bs*P_ + pbase + pp)*C_ + c] = v;
    mn = fminf(mn, v); mx = fmaxf(mx, v);
  }
  mn = fminf(mn, __shfl_xor(mn, 32));
  mx = fmaxf(mx, __shfl_xor(mx, 32));
  int wid = t >> 6;
  if ((t & 63) < 32){ rmn[wid*32 + c] = mn; rmx[wid*32 + c] = mx; }
  __syncthreads();
  if (t < 32){
    float m0 = rmn[t], M0 = rmx[t];
    #pragma unroll
    for (int w = 1; w < 8; ++w){ m0 = fminf(m0, rmn[w*32+t]); M0 = fmaxf(M0, rmx[w*32+t]); }
    pmm[((bs*4 + part)*32 + t)*2]     = m0;
    pmm[((bs*4 + part)*32 + t)*2 + 1] = M0;
  }
}

// ---------------- K2b: one-shot weight transpose for k_mid coalescing ----------
// grid = NM_INV blocks x 256
__global__ __launch_bounds__(256) void k_wt(
    const float* __restrict__ w1s_re, const float* __restrict__ w1s_im,
    const float* __restrict__ w2s_re, const float* __restrict__ w2s_im,
    const float* __restrict__ w1_re,  const float* __restrict__ w1_im,
    const float* __restrict__ w2_re,  const float* __restrict__ w2_im,
    const float* __restrict__ w1sb_re,const float* __restrict__ w1sb_im,
    const float* __restrict__ w2sb_re,const float* __restrict__ w2sb_im,
    float* __restrict__ w1t, float* __restrict__ w1st, float* __restrict__ w1sbt){
  int q = blockIdx.x;
  int t = threadIdx.x;
  bool p1 = (q < 300);
  int x = p1 ? q % 25 : q - 300;
  int y = p1 ? q / 25 : 12;
  for (int idx = t; idx < 1024; idx += 256){
    float wre, wim;
    if (p1){ int wi = (idx*25 + x)*12 + y; wre = w1_re[wi]; wim = w1_im[wi]; }
    else   { int wi = idx*13 + x;          wre = w2_re[wi]; wim = w2_im[wi]; }
    w1t[(size_t)(q*1024 + idx)*2]     = wre;
    w1t[(size_t)(q*1024 + idx)*2 + 1] = wim;
  }
  if (t < 8){
    int s = t;
    float a, b2, c2, d2;
    if (p1){ int wi = (s*25+x)*12+y; a=w1s_re[wi]; b2=w1s_im[wi]; c2=w1sb_re[wi]; d2=w1sb_im[wi]; }
    else   { int wi = s*13+x;        a=w2s_re[wi]; b2=w2s_im[wi]; c2=w2sb_re[wi]; d2=w2sb_im[wi]; }
    w1st[(q*8+s)*2]   = a;  w1st[(q*8+s)*2+1]  = b2;
    w1sbt[(q*8+s)*2]  = c2; w1sbt[(q*8+s)*2+1] = d2;
  }
}

// ---------------- K3: forward NUDFT as tiled dense MAC ----------------
// grid = (bs 32) x (mode-tile 6) x (p-part 2) = 384 blocks, 448 threads = 56 m x 8 cq
__global__ __launch_bounds__(448) void k_fwd(const float* __restrict__ om,
                                             const float* __restrict__ xg_t,
                                             float* __restrict__ coef_part){
  int blk = blockIdx.x;
  int part = blk & 1;
  int tile = (blk >> 1) % 6;
  int bs   = blk / 12;
  int t = threadIdx.x;
  int ml = t >> 3;          // 0..55
  int q  = t & 7;           // c-quad
  int mf = tile*56 + ml;
  int mfc = min(mf, NM_FWD-1);
  int xo = mfc / 13, yo = mfc - xo*13;
  float kx = (float)(xo - 12), ky = (float)(yo - 12);
  __shared__ float o0s[512], o1s[512];
  __shared__ __align__(16) float xgs[64*32];
  __shared__ float Wre[56*68], Wim[56*68];
  const float* om0 = om + bs*2*P_;
  const float* om1 = om0 + P_;
  for (int i = t; i < 512; i += 448){
    o0s[i] = om0[part*512 + i];
    o1s[i] = om1[part*512 + i];
  }
  float ar[4] = {0,0,0,0}, ai[4] = {0,0,0,0};
  for (int ch = 0; ch < 8; ++ch){
    int pbase = part*512 + ch*64;
    __syncthreads();
    for (int i = t; i < 512; i += 448){
      ((float4*)xgs)[i] = ((const float4*)xg_t)[(bs*P_ + pbase + (i>>3))*8 + (i&7)];
    }
    {
      int ps = t & 7;
      #pragma unroll
      for (int k = 0; k < 8; ++k){
        int p = ps + k*8;
        float th = o0s[ch*64 + p]*kx + o1s[ch*64 + p]*ky;
        float sn, cs; __sincosf(th, &sn, &cs);
        Wre[ml*68 + p] = cs;
        Wim[ml*68 + p] = sn;
      }
    }
    __syncthreads();
    #pragma unroll 8
    for (int p = 0; p < 64; ++p){
      float4 g4 = *(const float4*)&xgs[p*32 + q*4];
      float wre = Wre[ml*68 + p], wim = Wim[ml*68 + p];
      ar[0] += g4.x*wre; ai[0] += g4.x*wim;
      ar[1] += g4.y*wre; ai[1] += g4.y*wim;
      ar[2] += g4.z*wre; ai[2] += g4.z*wim;
      ar[3] += g4.w*wre; ai[3] += g4.w*wim;
    }
  }
  if (mf < NM_FWD){
    float* dst = coef_part + (size_t)((part*32 + bs)*NM_FWD + mf)*64 + q*8;
    #pragma unroll
    for (int j = 0; j < 4; ++j){
      dst[j*2]     = ar[j]*NORM_F;     // Re: sum g*cos
      dst[j*2 + 1] = -ai[j]*NORM_F;    // Im of e^{-i phi}: -sum g*sin
    }
  }
}

// ---------------- K4: spectral sandwich (transposed weights, coalesced) --------
// grid = b*313 blocks (q in y-major order), 64 threads; halves split serial loops
__global__ __launch_bounds__(64) void k_mid(const float* __restrict__ coef_part,
    const float* __restrict__ w1t, const float* __restrict__ w1st,
    const float* __restrict__ w1sbt, float* __restrict__ zbuf){
  int blk = blockIdx.x;
  int b = blk / NM_INV, q = blk - b*NM_INV;
  int lane = threadIdx.x;
  int o = lane & 31;
  int hi = lane >> 5;
  bool p1 = (q < 300);
  int x = p1 ? q % 25 : q - 300;
  int y = p1 ? q / 25 : 12;
  int mf = x*13 + y;
  __shared__ float iv[64];
  // phase 1: s-contract; lower lanes take part 0, upper part 1
  float are = 0.f, aim = 0.f;
  #pragma unroll
  for (int s = 0; s < 8; ++s){
    const float* cp = coef_part + (size_t)((hi*32 + b*8 + s)*NM_FWD + mf)*64 + o*2;
    float cre = cp[0], cim = cp[1];
    float wre = w1st[(q*8+s)*2], wim = w1st[(q*8+s)*2+1];
    are += cre*wre - cim*wim;
    aim += cre*wim + cim*wre;
  }
  are += __shfl_xor(are, 32);
  aim += __shfl_xor(aim, 32);
  if (hi == 0){ iv[o*2] = are; iv[o*2+1] = aim; }
  __syncthreads();
  // phase 2: 32x32 channel mix; halves split the i-loop; w1t loads coalesced
  float ore = 0.f, oim = 0.f;
  #pragma unroll
  for (int ii = 0; ii < 16; ++ii){
    int i = hi*16 + ii;
    float zre = iv[i*2], zim = iv[i*2+1];
    const float* wp = w1t + (size_t)(q*1024 + i*32 + o)*2;
    float wre = wp[0], wim = wp[1];
    ore += zre*wre - zim*wim;
    oim += zre*wim + zim*wre;
  }
  ore += __shfl_xor(ore, 32);
  oim += __shfl_xor(oim, 32);
  // phase 3: s-broadcast; halves split the s-loop
  float scale = p1 ? 0.08f : ((x==12) ? 0.04f : 0.08f);
  #pragma unroll
  for (int si = 0; si < 4; ++si){
    int s = hi*4 + si;
    float wre = w1sbt[(q*8+s)*2], wim = w1sbt[(q*8+s)*2+1];
    float zre = (ore*wre - oim*wim)*scale;
    float zim = (ore*wim + oim*wre)*scale;
    size_t oi = (size_t)((b*8 + s)*NM_INV + q)*64 + o*2;
    zbuf[oi] = zre; zbuf[oi+1] = zim;
  }
}

// ---------------- K5: inverse NUDFT, register-recurrence F, Z broadcast --------
// grid = (bs 32) x (p-tile 16) = 512 blocks, 256 threads = 4 oq x 64 pl
// mode order q = y*25+x (y=0..11), then 300+x (y=12): one unified 25-row recurrence
__global__ __launch_bounds__(256) void k_inv(const float* __restrict__ om,
                                             const float* __restrict__ zbuf,
                                             float* __restrict__ routc){
  int blk = blockIdx.x;
  int pt = blk & 15, bs = blk >> 4;
  int p0 = pt*64;
  int t = threadIdx.x;
  int oq = t >> 6, pl = t & 63;
  __shared__ __align__(16) float Zs[64*64];
  const float* zb = zbuf + (size_t)bs*NM_INV*64;
  float o0 = om[bs*2*P_ + p0 + pl];
  float o1 = om[bs*2*P_ + P_ + p0 + pl];
  float d0s, d0c; __sincosf(o0, &d0s, &d0c);            // e^{i*o0}
  float d1s, d1c; __sincosf(o1, &d1s, &d1c);            // e^{i*o1}
  float rs0, rc0; __sincosf(12.f*(o0+o1), &rs0, &rc0);
  float rre = rc0, rim = -rs0;                          // e^{-12i(o0+o1)} = row y=0 start
  float fre = rre, fim = rim;
  int rowc = 0;
  float acc[8] = {0,0,0,0,0,0,0,0};
  for (int chv = 0; chv < 5; ++chv){
    int m0 = chv*64;
    int mcount = min(64, NM_INV - m0);
    __syncthreads();
    for (int i = t*4; i < mcount*64; i += 1024)
      *(float4*)&Zs[i] = *(const float4*)&zb[m0*64 + i];
    __syncthreads();
    const float* zrow = Zs + oq*16;
    for (int m = 0; m < mcount; ++m){
      if (rowc == 25){                                  // next y-row (uniform branch)
        float nr = rre*d1c - rim*d1s;
        float ni = rre*d1s + rim*d1c;
        rre = nr; rim = ni;
        fre = rre; fim = rim;
        rowc = 0;
      }
      float4 za = *(const float4*)&zrow[m*64];
      float4 zb4 = *(const float4*)&zrow[m*64 + 4];
      float4 zc = *(const float4*)&zrow[m*64 + 8];
      float4 zd = *(const float4*)&zrow[m*64 + 12];
      acc[0] += za.x*fre  - za.y*fim;
      acc[1] += za.z*fre  - za.w*fim;
      acc[2] += zb4.x*fre - zb4.y*fim;
      acc[3] += zb4.z*fre - zb4.w*fim;
      acc[4] += zc.x*fre  - zc.y*fim;
      acc[5] += zc.z*fre  - zc.w*fim;
      acc[6] += zd.x*fre  - zd.y*fim;
      acc[7] += zd.z*fre  - zd.w*fim;
      float nf = fre*d0c - fim*d0s;                     // f *= e^{i*o0} (x-step)
      float ni = fre*d0s + fim*d0c;
      fre = nf; fim = ni;
      ++rowc;
    }
  }
  float* outp = routc + (size_t)(bs*C_ + oq*8)*P_ + p0 + pl;
  #pragma unroll
  for (int j = 0; j < 8; ++j)
    outp[(size_t)j*P_] = acc[j];
}

// ---------------- K6: renorm + inverse-permutation scatter ----------------
// grid = (b,s,o) = 1024 blocks, 256 threads x 4 points
__global__ __launch_bounds__(256) void k_fin(const float* __restrict__ routc,
                                             const float* __restrict__ pmm,
                                             const int* __restrict__ ind,
                                             float* __restrict__ out){
  int blk = blockIdx.x;
  int o = blk & 31, s = (blk >> 5) & 7, b = blk >> 8;
  int bs = b*8 + s;
  int t = threadIdx.x;
  __shared__ float red[256];
  const float* rr = routc + (size_t)(bs*C_ + o)*P_;
  float v[4]; float mn = 1e30f, mx = -1e30f;
  #pragma unroll
  for (int k = 0; k < 4; ++k){
    v[k] = rr[t + k*256];
    mn = fminf(mn, v[k]); mx = fmaxf(mx, v[k]);
  }
  mn = blk_red(mn, red, true);
  mx = blk_red(mx, red, false);
  float xmn = 1e30f, xmx = -1e30f;
  #pragma unroll
  for (int part = 0; part < 4; ++part){
    xmn = fminf(xmn, pmm[((bs*4+part)*32 + o)*2]);
    xmx = fmaxf(xmx, pmm[((bs*4+part)*32 + o)*2 + 1]);
  }
  float scale = (xmx - xmn) / (mx - mn + 1e-6f);
  const int* indb = ind + b*N_ + s*P_;
  float* outb = out + (size_t)(b*C_ + o)*N_;
  #pragma unroll
  for (int k = 0; k < 4; ++k){
    int p = t + k*256;
    outb[indb[p]] = (v[k] - mn)*scale + xmn;
  }
}

extern "C" void kernel_launch(void* const* d_in, const int* in_sizes, int n_in,
                              void* d_out, int out_size, void* d_ws, size_t ws_size,
                              hipStream_t stream){
  const float* x      = (const float*)d_in[0];
  const float* loc    = (const float*)d_in[1];
  const int*   ind    = (const int*)  d_in[2];
  const float* w1s_re = (const float*)d_in[3];
  const float* w1s_im = (const float*)d_in[4];
  const float* w2s_re = (const float*)d_in[5];
  const float* w2s_im = (const float*)d_in[6];
  const float* w1_re  = (const float*)d_in[7];
  const float* w1_im  = (const float*)d_in[8];
  const float* w2_re  = (const float*)d_in[9];
  const float* w2_im  = (const float*)d_in[10];
  const float* w1sb_re= (const float*)d_in[11];
  const float* w1sb_im= (const float*)d_in[12];
  const float* w2sb_re= (const float*)d_in[13];
  const float* w2sb_im= (const float*)d_in[14];
  float* out = (float*)d_out;

  float* ws = (float*)d_ws;
  float* om        = ws;                    // (B,S,2,P)              =    65,536
  float* xg_t      = om + 65536;            // (B,S,P,C)              = 1,048,576  (aliased by routc)
  float* pmm       = xg_t + 1048576;        // (B,S,4part,C,2)        =     8,192
  float* coef_part = pmm + 8192;            // (2,B,S,325,C,2)        = 1,331,200
  float* zbuf      = coef_part + 1331200;   // (B,S,313,C,2)          =   641,024
  float* w1t       = zbuf + 641024;         // (313,32,32,2)          =   641,024
  float* w1st      = w1t + 641024;          // (313,8,2)              =     5,008
  float* w1sbt     = w1st + 5008;           // (313,8,2)              =     5,008
  float* routc     = xg_t;                  // (B,S,C,P) alias: xg_t dead after k_fwd

  k_om <<<32,   256, 0, stream>>>(loc, ind, om);
  k_xg <<<128,  512, 0, stream>>>(x, ind, xg_t, pmm);
  k_wt <<<NM_INV, 256, 0, stream>>>(w1s_re, w1s_im, w2s_re, w2s_im,
                                    w1_re, w1_im, w2_re, w2_im,
                                    w1sb_re, w1sb_im, w2sb_re, w2sb_im,
                                    w1t, w1st, w1sbt);
  k_fwd<<<384,  448, 0, stream>>>(om, xg_t, coef_part);
  k_mid<<<4*NM_INV, 64, 0, stream>>>(coef_part, w1t, w1st, w1sbt, zbuf);
  k_inv<<<512,  256, 0, stream>>>(om, zbuf, routc);
  k_fin<<<1024, 256, 0, stream>>>(routc, pmm, ind, out);
}